// Round 5
// baseline (720.047 us; speedup 1.0000x reference)
//
#include <hip/hip_runtime.h>
#include <math.h>

#define D    6
#define S    128
#define H    128
#define WIN  16
#define BB   8
#define TT   513
#define NW   32
#define OUTD 10

// ---- device-global scratch ----
__device__ float g_lvl1[BB * NW * D];
__device__ float g_area[BB * NW * D * D];
__device__ float g_h0[BB * S];
__device__ float g_hist[BB * (NW + 1) * S];

__device__ __forceinline__ float sp(float x) {
    return (x > 20.f) ? x : log1pf(expf(x));
}
__device__ __forceinline__ float sigm(float x) {
    return 1.f / (1.f + expf(-x));
}
__device__ __forceinline__ float dot4(float4 a, float4 b, float acc) {
    return fmaf(a.x, b.x, fmaf(a.y, b.y, fmaf(a.z, b.z, fmaf(a.w, b.w, acc))));
}

// ---- LDS layout (float offsets) ----
#define O_W0  0        // [128 r][128 k] row-major (as input)
#define O_W1  16384
#define O_PS  32768    // psum [4 c][6 j][128 r]  (3072) ; aliased psumV [2][768]
#define O_U   35840    // [6][128] tangents U ; later T2
#define O_T   36608    // [6][128] T1 ; later bterm
#define O_V   37376    // [768] V
#define O_H   38144    // h double buffer [2][128]
#define O_U1  38400
#define O_SG1 38528
#define O_U2  38656
#define O_SG2 38784
#define O_B0  38912
#define O_B1  39040
#define O_L1  39168
#define O_AR  39174
#define SMTOT 39216    // 156,864 B

// ---- K2: windowed log-signature + init MLP ----
__global__ __launch_bounds__(256) void k_sig(
        const float* __restrict__ x,
        const float* __restrict__ Wi0, const float* __restrict__ bi0,
        const float* __restrict__ Wi1, const float* __restrict__ bi1,
        const float* __restrict__ Wi2, const float* __restrict__ bi2) {
    const int b = blockIdx.x;
    const int tid = threadIdx.x;
    __shared__ float dxs[NW][WIN][D];
    __shared__ float cums[NW][WIN][D];
    __shared__ float ua[H], ub[H];

    const float* xb = x + (size_t)b * TT * D;

    if (tid < NW * D) {
        int w = tid / D, i = tid % D;
        float run = 0.f;
        float prev = xb[(w * WIN) * D + i];
        for (int k = 0; k < WIN; ++k) {
            float cur = xb[(w * WIN + k + 1) * D + i];
            float d = cur - prev; prev = cur;
            dxs[w][k][i] = d;
            cums[w][k][i] = run;
            run += d;
        }
        g_lvl1[(b * NW + w) * D + i] = run;
    }
    __syncthreads();
    for (int e = tid; e < NW * D * D; e += blockDim.x) {
        int w = e / (D * D); int rem = e % (D * D);
        int i = rem / D, j = rem % D;
        float s = 0.f;
        for (int k = 0; k < WIN; ++k)
            s += cums[w][k][i] * dxs[w][k][j] - cums[w][k][j] * dxs[w][k][i];
        g_area[(b * NW + w) * (D * D) + rem] = 0.5f * s;
    }
    if (tid < H) {
        float z = bi0[tid];
        for (int k = 0; k < D; ++k) z += Wi0[tid * D + k] * xb[k];
        ua[tid] = sp(z);
    }
    __syncthreads();
    if (tid < H) {
        float z = bi1[tid];
        for (int k = 0; k < H; ++k) z += Wi1[tid * H + k] * ua[k];
        ub[tid] = sp(z);
    }
    __syncthreads();
    if (tid < H) {
        float z = bi2[tid];
        for (int k = 0; k < H; ++k) z += Wi2[tid * H + k] * ub[k];
        g_h0[b * S + tid] = z;
    }
}

// W2 register block: 32 NAMED float4 (no arrays -> no scratch demotion)
#define W2_DECL \
    float4 e0,e1,e2,e3,e4,e5,e6,e7,e8,e9,e10,e11,e12,e13,e14,e15, \
           o0,o1,o2,o3,o4,o5,o6,o7,o8,o9,o10,o11,o12,o13,o14,o15;
#define W2_LOAD1(i) \
    e##i = W24[(2 * m) * 32 + kh * 16 + i]; \
    o##i = W24[(2 * m + 1) * 32 + kh * 16 + i];
#define W2_LOAD_ALL \
    W2_LOAD1(0)  W2_LOAD1(1)  W2_LOAD1(2)  W2_LOAD1(3) \
    W2_LOAD1(4)  W2_LOAD1(5)  W2_LOAD1(6)  W2_LOAD1(7) \
    W2_LOAD1(8)  W2_LOAD1(9)  W2_LOAD1(10) W2_LOAD1(11) \
    W2_LOAD1(12) W2_LOAD1(13) W2_LOAD1(14) W2_LOAD1(15)
#define W2_ACC1(i, SRC) \
    { float4 uu = (SRC)[i]; a0 = dot4(e##i, uu, a0); a1 = dot4(o##i, uu, a1); }
#define W2_ACC_ALL(SRC) \
    W2_ACC1(0,  SRC) W2_ACC1(1,  SRC) W2_ACC1(2,  SRC) W2_ACC1(3,  SRC) \
    W2_ACC1(4,  SRC) W2_ACC1(5,  SRC) W2_ACC1(6,  SRC) W2_ACC1(7,  SRC) \
    W2_ACC1(8,  SRC) W2_ACC1(9,  SRC) W2_ACC1(10, SRC) W2_ACC1(11, SRC) \
    W2_ACC1(12, SRC) W2_ACC1(13, SRC) W2_ACC1(14, SRC) W2_ACC1(15, SRC)

// ---- K3: the scan ----
__global__ __launch_bounds__(768, 3) void k_scan(
        const float* __restrict__ bv0, const float* __restrict__ bv1,
        const float* __restrict__ bv2,
        const float* __restrict__ Wv0, const float* __restrict__ Wv1,
        const float* __restrict__ Wv2) {
    __shared__ float sm[SMTOT];
    const int b = blockIdx.x, tid = threadIdx.x;
    const int kh = (tid >= 384) ? 1 : 0;      // k-half for W2 stages
    const int m  = tid - kh * 384;            // row-pair index 0..383
    const int rp  = tid & 63;                 // row-pair for W0/W1 stages
    const int c4  = tid >> 6;                 // k-chunk 0..3 (when tid<256)
    const int key = rp & 7;
    const int jj = tid >> 7, rr = tid & 127;  // 6x128 decomposition
    const int j6 = m >> 6;                    // j-block of this thread's W2 rows

    // stage W0, W1 (row-major, verbatim)
    {
        float4* d = (float4*)(sm + O_W0);
        const float4* s0 = (const float4*)Wv0;
        const float4* s1 = (const float4*)Wv1;
        for (int i = tid; i < 4096; i += 768) { d[i] = s0[i]; d[4096 + i] = s1[i]; }
    }
    // W2 row-pair (rows 2m, 2m+1), k-half kh, in 32 named float4 registers
    W2_DECL
    const float4* W24 = (const float4*)Wv2;   // [768][32]
    W2_LOAD_ALL
    if (tid < 128) {
        sm[O_B0 + tid] = bv0[tid]; sm[O_B1 + tid] = bv1[tid];
        float h0v = g_h0[b * 128 + tid];
        sm[O_H + tid] = h0v;
        g_hist[(b * (NW + 1)) * 128 + tid] = h0v;
    }
    __syncthreads();

    const float4* W04 = (const float4*)(sm + O_W0);
    const float4* W14 = (const float4*)(sm + O_W1);

    int p = 0;
    for (int t = 0; t < NW; ++t) {
        // sig loads (wave 11) — consumed after >=2 barriers
        if (tid >= 704) {
            int q = tid - 704;
            if (q < 6)       sm[O_L1 + q]     = g_lvl1[(b * NW + t) * D + q];
            else if (q < 42) sm[O_AR + q - 6] = g_area[(b * NW + t) * 36 + q - 6];
        }
        // ---- S1: psum[c][0][r] = W0[rows] . h ----
        if (tid < 256) {
            float a0 = 0.f, a1 = 0.f;
            const float4* H4 = (const float4*)(sm + O_H + p * 128);
            #pragma unroll
            for (int q = 0; q < 8; ++q) {
                int qq = c4 * 8 + (q ^ key);
                float4 we = W04[(2 * rp) * 32 + qq];
                float4 wo = W04[(2 * rp + 1) * 32 + qq];
                float4 hv = H4[qq];
                a0 = dot4(we, hv, a0); a1 = dot4(wo, hv, a1);
            }
            *(float2*)&sm[O_PS + (c4 * 6) * 128 + 2 * rp] = make_float2(a0, a1);
        }
        __syncthreads();
        if (tid < 128) {
            float z = sm[O_B0 + tid];
            #pragma unroll
            for (int c = 0; c < 4; ++c) z += sm[O_PS + (c * 6) * 128 + tid];
            sm[O_U1 + tid] = sp(z); sm[O_SG1 + tid] = sigm(z);
        }
        __syncthreads();
        // ---- S2: psum = W1[rows] . u1 ----
        if (tid < 256) {
            float a0 = 0.f, a1 = 0.f;
            const float4* U14 = (const float4*)(sm + O_U1);
            #pragma unroll
            for (int q = 0; q < 8; ++q) {
                int qq = c4 * 8 + (q ^ key);
                float4 we = W14[(2 * rp) * 32 + qq];
                float4 wo = W14[(2 * rp + 1) * 32 + qq];
                float4 hv = U14[qq];
                a0 = dot4(we, hv, a0); a1 = dot4(wo, hv, a1);
            }
            *(float2*)&sm[O_PS + (c4 * 6) * 128 + 2 * rp] = make_float2(a0, a1);
        }
        __syncthreads();
        if (tid < 128) {
            float z = sm[O_B1 + tid];
            #pragma unroll
            for (int c = 0; c < 4; ++c) z += sm[O_PS + (c * 6) * 128 + tid];
            sm[O_U2 + tid] = sp(z); sm[O_SG2 + tid] = sigm(z);
        }
        __syncthreads();
        // ---- S3: psumV[kh][row] = W2rows . u2 (k-half) ----
        {
            float a0 = 0.f, a1 = 0.f;
            const float4* U24 = (const float4*)(sm + O_U2) + kh * 16;
            W2_ACC_ALL(U24)
            *(float2*)&sm[O_PS + kh * 768 + 2 * m] = make_float2(a0, a1);
        }
        __syncthreads();
        // ---- R3: V[row] = tanh(sum + b2) ----
        {
            float z = bv2[tid] + sm[O_PS + tid] + sm[O_PS + 768 + tid];
            sm[O_V + tid] = tanhf(z);
        }
        __syncthreads();
        // ---- UF: U[j][r] = sum_i area[i][j] V[i*128+r]; h-next init ----
        {
            float u = 0.f;
            #pragma unroll
            for (int i = 0; i < 6; ++i)
                u = fmaf(sm[O_AR + i * 6 + jj], sm[O_V + i * 128 + rr], u);
            sm[O_U + jj * 128 + rr] = u;
            if (tid < 128) {
                float xh = sm[O_H + p * 128 + tid];
                #pragma unroll
                for (int i = 0; i < 6; ++i)
                    xh = fmaf(sm[O_L1 + i], sm[O_V + i * 128 + tid], xh);
                sm[O_H + (p ^ 1) * 128 + tid] = xh;
            }
        }
        __syncthreads();
        // ---- S4: psum[c][j][r] = W0[rows] . U_j ----
        if (tid < 256) {
            float a0[6] = {0,0,0,0,0,0}, a1[6] = {0,0,0,0,0,0};
            const float4* U4 = (const float4*)(sm + O_U);
            #pragma unroll
            for (int q = 0; q < 8; ++q) {
                int qq = c4 * 8 + (q ^ key);
                float4 we = W04[(2 * rp) * 32 + qq];
                float4 wo = W04[(2 * rp + 1) * 32 + qq];
                #pragma unroll
                for (int j = 0; j < 6; ++j) {
                    float4 u = U4[j * 32 + qq];
                    a0[j] = dot4(we, u, a0[j]); a1[j] = dot4(wo, u, a1[j]);
                }
            }
            #pragma unroll
            for (int j = 0; j < 6; ++j)
                *(float2*)&sm[O_PS + (c4 * 6 + j) * 128 + 2 * rp] = make_float2(a0[j], a1[j]);
        }
        __syncthreads();
        // ---- R4: T1[j][r] = sg1[r] * sum_c ----
        {
            float s = sm[O_PS + jj * 128 + rr] + sm[O_PS + (6 + jj) * 128 + rr]
                    + sm[O_PS + (12 + jj) * 128 + rr] + sm[O_PS + (18 + jj) * 128 + rr];
            sm[O_T + jj * 128 + rr] = sm[O_SG1 + rr] * s;
        }
        __syncthreads();
        // ---- S5: psum[c][j][r] = W1[rows] . T1_j ----
        if (tid < 256) {
            float a0[6] = {0,0,0,0,0,0}, a1[6] = {0,0,0,0,0,0};
            const float4* T4 = (const float4*)(sm + O_T);
            #pragma unroll
            for (int q = 0; q < 8; ++q) {
                int qq = c4 * 8 + (q ^ key);
                float4 we = W14[(2 * rp) * 32 + qq];
                float4 wo = W14[(2 * rp + 1) * 32 + qq];
                #pragma unroll
                for (int j = 0; j < 6; ++j) {
                    float4 u = T4[j * 32 + qq];
                    a0[j] = dot4(we, u, a0[j]); a1[j] = dot4(wo, u, a1[j]);
                }
            }
            #pragma unroll
            for (int j = 0; j < 6; ++j)
                *(float2*)&sm[O_PS + (c4 * 6 + j) * 128 + 2 * rp] = make_float2(a0[j], a1[j]);
        }
        __syncthreads();
        // ---- R5: T2[j][r] = sg2[r] * sum_c  (into O_U) ----
        {
            float s = sm[O_PS + jj * 128 + rr] + sm[O_PS + (6 + jj) * 128 + rr]
                    + sm[O_PS + (12 + jj) * 128 + rr] + sm[O_PS + (18 + jj) * 128 + rr];
            sm[O_U + jj * 128 + rr] = sm[O_SG2 + rr] * s;
        }
        __syncthreads();
        // ---- S6: psumV[kh][row] = W2rows . T2_{j(row)} ----
        {
            float a0 = 0.f, a1 = 0.f;
            const float4* T24 = (const float4*)(sm + O_U) + j6 * 32 + kh * 16;
            W2_ACC_ALL(T24)
            *(float2*)&sm[O_PS + kh * 768 + 2 * m] = make_float2(a0, a1);
        }
        __syncthreads();
        // ---- R6: bterm[row] = (1-V^2)*(sum)  (into O_T) ----
        {
            float v = sm[O_V + tid];
            sm[O_T + tid] = (1.f - v * v) * (sm[O_PS + tid] + sm[O_PS + 768 + tid]);
        }
        __syncthreads();
        // ---- H: h update + hist ----
        if (tid < 128) {
            float xh = sm[O_H + (p ^ 1) * 128 + tid];
            #pragma unroll
            for (int j = 0; j < 6; ++j) xh += sm[O_T + j * 128 + tid];
            sm[O_H + (p ^ 1) * 128 + tid] = xh;
            g_hist[(b * (NW + 1) + t + 1) * 128 + tid] = xh;
        }
        p ^= 1;
        __syncthreads();
    }
}

// ---- K4: readout ----
__global__ __launch_bounds__(384) void k_read(const float* __restrict__ Wr,
                                              const float* __restrict__ br,
                                              float* __restrict__ out) {
    const int b = blockIdx.x, e = threadIdx.x;
    if (e < (NW + 1) * OUTD) {
        int t = e / OUTD, o = e % OUTD;
        float z = br[o];
        const float4* hrow = (const float4*)&g_hist[(b * (NW + 1) + t) * 128];
        const float4* wrow = (const float4*)&Wr[o * 128];
        float z0 = 0, z1 = 0, z2 = 0, z3 = 0;
        #pragma unroll 8
        for (int s4 = 0; s4 < 32; ++s4) {
            float4 hv = hrow[s4]; float4 wv = wrow[s4];
            z0 = fmaf(hv.x, wv.x, z0); z1 = fmaf(hv.y, wv.y, z1);
            z2 = fmaf(hv.z, wv.z, z2); z3 = fmaf(hv.w, wv.w, z3);
        }
        out[(b * (NW + 1) + t) * OUTD + o] = z + ((z0 + z1) + (z2 + z3));
    }
}

extern "C" void kernel_launch(void* const* d_in, const int* in_sizes, int n_in,
                              void* d_out, int out_size, void* d_ws, size_t ws_size,
                              hipStream_t stream) {
    const float* x   = (const float*)d_in[0];
    const float* Wi0 = (const float*)d_in[1];
    const float* bi0 = (const float*)d_in[2];
    const float* Wi1 = (const float*)d_in[3];
    const float* bi1 = (const float*)d_in[4];
    const float* Wi2 = (const float*)d_in[5];
    const float* bi2 = (const float*)d_in[6];
    const float* Wv0 = (const float*)d_in[7];
    const float* bv0 = (const float*)d_in[8];
    const float* Wv1 = (const float*)d_in[9];
    const float* bv1 = (const float*)d_in[10];
    const float* Wv2 = (const float*)d_in[11];
    const float* bv2 = (const float*)d_in[12];
    const float* Wr  = (const float*)d_in[13];
    const float* br  = (const float*)d_in[14];
    float* out = (float*)d_out;

    hipLaunchKernelGGL(k_sig,  dim3(BB), dim3(256), 0, stream,
                       x, Wi0, bi0, Wi1, bi1, Wi2, bi2);
    hipLaunchKernelGGL(k_scan, dim3(BB), dim3(768), 0, stream,
                       bv0, bv1, bv2, Wv0, Wv1, Wv2);
    hipLaunchKernelGGL(k_read, dim3(BB), dim3(384), 0, stream, Wr, br, out);
}

// Round 7
// 621.545 us; speedup vs baseline: 1.1585x; 1.1585x over previous
//
#include <hip/hip_runtime.h>
#include <math.h>

#define D    6
#define S    128
#define H    128
#define WIN  16
#define BB   8
#define TT   513
#define NW   32
#define OUTD 10

// ---- device-global scratch ----
__device__ float g_lvl1[BB * NW * D];
__device__ float g_area[BB * NW * D * D];
__device__ float g_h0[BB * S];
__device__ float g_hist[BB * (NW + 1) * S];

__device__ __forceinline__ float sp(float x) {
    return (x > 20.f) ? x : log1pf(expf(x));
}
__device__ __forceinline__ float sigm(float x) {
    return 1.f / (1.f + expf(-x));
}
__device__ __forceinline__ float dot4(float4 a, float4 b, float acc) {
    return fmaf(a.x, b.x, fmaf(a.y, b.y, fmaf(a.z, b.z, fmaf(a.w, b.w, acc))));
}

// ---- LDS layout (float offsets) ----
#define O_W0   0        // [128 r][128 k] fp32 row-major
#define O_W1   16384
#define O_PS   32768    // psum [4 c][6 j][128 r]
#define O_U    35840    // [6][128] tangents U ; later T2
#define O_T    36608    // [6][128] T1 ; later bterm [768]
#define O_V    37376    // [768]
#define O_H    38144    // h double buffer [2][128]
#define O_U1   38400
#define O_U2   38528
#define O_SG1  38656
#define O_SG2  38784
#define O_B0   38912
#define O_B1   39040
#define O_SIG  39168    // [2][44]: 6 lvl1 + 36 area, double-buffered
#define SMTOT  39256    // 157,024 B

// ---- K2: windowed log-signature + init MLP ----
__global__ __launch_bounds__(256) void k_sig(
        const float* __restrict__ x,
        const float* __restrict__ Wi0, const float* __restrict__ bi0,
        const float* __restrict__ Wi1, const float* __restrict__ bi1,
        const float* __restrict__ Wi2, const float* __restrict__ bi2) {
    const int b = blockIdx.x;
    const int tid = threadIdx.x;
    __shared__ float dxs[NW][WIN][D];
    __shared__ float cums[NW][WIN][D];
    __shared__ float ua[H], ub[H];

    const float* xb = x + (size_t)b * TT * D;

    if (tid < NW * D) {
        int w = tid / D, i = tid % D;
        float run = 0.f;
        float prev = xb[(w * WIN) * D + i];
        for (int k = 0; k < WIN; ++k) {
            float cur = xb[(w * WIN + k + 1) * D + i];
            float d = cur - prev; prev = cur;
            dxs[w][k][i] = d;
            cums[w][k][i] = run;
            run += d;
        }
        g_lvl1[(b * NW + w) * D + i] = run;
    }
    __syncthreads();
    for (int e = tid; e < NW * D * D; e += blockDim.x) {
        int w = e / (D * D); int rem = e % (D * D);
        int i = rem / D, j = rem % D;
        float s = 0.f;
        for (int k = 0; k < WIN; ++k)
            s += cums[w][k][i] * dxs[w][k][j] - cums[w][k][j] * dxs[w][k][i];
        g_area[(b * NW + w) * (D * D) + rem] = 0.5f * s;
    }
    if (tid < H) {
        float z = bi0[tid];
        for (int k = 0; k < D; ++k) z += Wi0[tid * D + k] * xb[k];
        ua[tid] = sp(z);
    }
    __syncthreads();
    if (tid < H) {
        float z = bi1[tid];
        for (int k = 0; k < H; ++k) z += Wi1[tid * H + k] * ua[k];
        ub[tid] = sp(z);
    }
    __syncthreads();
    if (tid < H) {
        float z = bi2[tid];
        for (int k = 0; k < H; ++k) z += Wi2[tid * H + k] * ub[k];
        g_h0[b * S + tid] = z;
    }
}

// ---- W2: 96 NAMED float4 per thread (3 rows x 32 quads), fp32 ----
#define W2_FOREACH(X) \
    X(0,32,64)  X(1,33,65)  X(2,34,66)  X(3,35,67)  X(4,36,68)  X(5,37,69) \
    X(6,38,70)  X(7,39,71)  X(8,40,72)  X(9,41,73)  X(10,42,74) X(11,43,75) \
    X(12,44,76) X(13,45,77) X(14,46,78) X(15,47,79) X(16,48,80) X(17,49,81) \
    X(18,50,82) X(19,51,83) X(20,52,84) X(21,53,85) X(22,54,86) X(23,55,87) \
    X(24,56,88) X(25,57,89) X(26,58,90) X(27,59,91) X(28,60,92) X(29,61,93) \
    X(30,62,94) X(31,63,95)

#define W2_DECL1(a,b,c) float4 wr##a, wr##b, wr##c;
#define W2_LOAD1(a,b,c) \
    wr##a = W24[base0 + (a)]; \
    wr##b = W24[base1 + (b) - 32]; \
    wr##c = W24[base2 + (c) - 64];
#define S3_Q(a,b,c) { \
    float4 u = U24[(a)]; \
    acc0 = dot4(wr##a, u, acc0); \
    acc1 = dot4(wr##b, u, acc1); \
    acc2 = dot4(wr##c, u, acc2); }
#define S6_Q(a,b,c) { \
    acc0 = dot4(wr##a, T2a[(a)], acc0); \
    acc1 = dot4(wr##b, T2b[(a)], acc1); \
    acc2 = dot4(wr##c, T2c[(a)], acc2); }

// ---- K3: the scan: 256 threads, 4 waves, W2 fully register-resident ----
__global__ __launch_bounds__(256, 1) void k_scan(
        const float* __restrict__ bv0, const float* __restrict__ bv1,
        const float* __restrict__ bv2,
        const float* __restrict__ Wv0, const float* __restrict__ Wv1,
        const float* __restrict__ Wv2) {
    __shared__ float sm[SMTOT];
    const int b = blockIdx.x, tid = threadIdx.x;
    const int rp  = tid & 63;        // row-pair for W0/W1 psum stages
    const int c4  = tid >> 6;        // k-chunk 0..3
    const int key = rp & 7;
    const int jr0 = tid >> 7;        // 0..1

    // stage W0, W1 into LDS (row-major, verbatim)
    {
        float4* d = (float4*)(sm + O_W0);
        const float4* s0 = (const float4*)Wv0;
        const float4* s1 = (const float4*)Wv1;
        for (int i = tid; i < 4096; i += 256) { d[i] = s0[i]; d[4096 + i] = s1[i]; }
    }
    // W2 rows {tid, tid+256, tid+512} in 96 named float4 registers
    W2_FOREACH(W2_DECL1)
    const float4* W24 = (const float4*)Wv2;   // [768][32]
    const int base0 = tid * 32, base1 = (tid + 256) * 32, base2 = (tid + 512) * 32;
    W2_FOREACH(W2_LOAD1)
    const float b2r0 = bv2[tid], b2r1 = bv2[tid + 256], b2r2 = bv2[tid + 512];
    if (tid < 128) {
        sm[O_B0 + tid] = bv0[tid]; sm[O_B1 + tid] = bv1[tid];
        float h0v = g_h0[b * 128 + tid];
        sm[O_H + tid] = h0v;
        g_hist[(b * (NW + 1)) * 128 + tid] = h0v;
    }
    if (tid >= 192) {               // sig for t=0 into buf 0
        int q = tid - 192;
        if (q < 42)
            sm[O_SIG + q] = (q < 6) ? g_lvl1[(b * NW) * 6 + q]
                                    : g_area[(b * NW) * 36 + q - 6];
    }
    __syncthreads();

    const float4* W04 = (const float4*)(sm + O_W0);
    const float4* W14 = (const float4*)(sm + O_W1);

    int p = 0;
    for (int t = 0; t < NW; ++t) {
        // prefetch sig for step t+1 into registers (written at H phase)
        float rsig = 0.f;
        if (tid >= 192) {
            int q = tid - 192;
            if (q < 42 && t + 1 < NW)
                rsig = (q < 6) ? g_lvl1[(b * NW + t + 1) * 6 + q]
                               : g_area[(b * NW + t + 1) * 36 + q - 6];
        }
        const int sb = O_SIG + (t & 1) * 44;

        // ---- S1: psum[c][0][r] = W0[row-pair] . h ----
        {
            float a0 = 0.f, a1 = 0.f;
            const float4* H4 = (const float4*)(sm + O_H + p * 128);
            #pragma unroll
            for (int q = 0; q < 8; ++q) {
                int qq = c4 * 8 + (q ^ key);
                float4 we = W04[(2 * rp) * 32 + qq];
                float4 wo = W04[(2 * rp + 1) * 32 + qq];
                float4 hv = H4[qq];
                a0 = dot4(we, hv, a0); a1 = dot4(wo, hv, a1);
            }
            *(float2*)&sm[O_PS + (c4 * 6) * 128 + 2 * rp] = make_float2(a0, a1);
        }
        __syncthreads();
        // ---- R1 ----
        if (tid < 128) {
            float z = sm[O_B0 + tid];
            #pragma unroll
            for (int c = 0; c < 4; ++c) z += sm[O_PS + (c * 6) * 128 + tid];
            sm[O_U1 + tid] = sp(z); sm[O_SG1 + tid] = sigm(z);
        }
        __syncthreads();
        // ---- S2: psum = W1[row-pair] . u1 ----
        {
            float a0 = 0.f, a1 = 0.f;
            const float4* U14 = (const float4*)(sm + O_U1);
            #pragma unroll
            for (int q = 0; q < 8; ++q) {
                int qq = c4 * 8 + (q ^ key);
                float4 we = W14[(2 * rp) * 32 + qq];
                float4 wo = W14[(2 * rp + 1) * 32 + qq];
                float4 hv = U14[qq];
                a0 = dot4(we, hv, a0); a1 = dot4(wo, hv, a1);
            }
            *(float2*)&sm[O_PS + (c4 * 6) * 128 + 2 * rp] = make_float2(a0, a1);
        }
        __syncthreads();
        // ---- R2 ----
        if (tid < 128) {
            float z = sm[O_B1 + tid];
            #pragma unroll
            for (int c = 0; c < 4; ++c) z += sm[O_PS + (c * 6) * 128 + tid];
            sm[O_U2 + tid] = sp(z); sm[O_SG2 + tid] = sigm(z);
        }
        __syncthreads();
        // ---- S3: V rows {tid, tid+256, tid+512} from register W2 ----
        float vl0, vl1, vl2;
        {
            float acc0 = 0.f, acc1 = 0.f, acc2 = 0.f;
            const float4* U24 = (const float4*)(sm + O_U2);
            W2_FOREACH(S3_Q)
            vl0 = tanhf(b2r0 + acc0);
            vl1 = tanhf(b2r1 + acc1);
            vl2 = tanhf(b2r2 + acc2);
            sm[O_V + tid] = vl0; sm[O_V + tid + 256] = vl1; sm[O_V + tid + 512] = vl2;
        }
        __syncthreads();
        // ---- UF: U[j][r] = sum_i area[i][j] V[i*128+r]; h-next init ----
        {
            #pragma unroll
            for (int s = 0; s < 3; ++s) {
                int e = tid + s * 256;
                int jj = e >> 7, rr = e & 127;
                float u = 0.f;
                #pragma unroll
                for (int i = 0; i < 6; ++i)
                    u = fmaf(sm[sb + 6 + i * 6 + jj], sm[O_V + i * 128 + rr], u);
                sm[O_U + jj * 128 + rr] = u;
            }
            if (tid < 128) {
                float xh = sm[O_H + p * 128 + tid];
                #pragma unroll
                for (int i = 0; i < 6; ++i)
                    xh = fmaf(sm[sb + i], sm[O_V + i * 128 + tid], xh);
                sm[O_H + (p ^ 1) * 128 + tid] = xh;
            }
        }
        __syncthreads();
        // ---- S4: psum[c][j][r] = W0[row-pair] . U_j ----
        {
            float a0[6] = {0,0,0,0,0,0}, a1[6] = {0,0,0,0,0,0};
            const float4* U4 = (const float4*)(sm + O_U);
            #pragma unroll
            for (int q = 0; q < 8; ++q) {
                int qq = c4 * 8 + (q ^ key);
                float4 we = W04[(2 * rp) * 32 + qq];
                float4 wo = W04[(2 * rp + 1) * 32 + qq];
                #pragma unroll
                for (int j = 0; j < 6; ++j) {
                    float4 u = U4[j * 32 + qq];
                    a0[j] = dot4(we, u, a0[j]); a1[j] = dot4(wo, u, a1[j]);
                }
            }
            #pragma unroll
            for (int j = 0; j < 6; ++j)
                *(float2*)&sm[O_PS + (c4 * 6 + j) * 128 + 2 * rp] = make_float2(a0[j], a1[j]);
        }
        __syncthreads();
        // ---- R4: T1[j][r] = sg1[r] * sum_c ----
        {
            #pragma unroll
            for (int s = 0; s < 3; ++s) {
                int e = tid + s * 256;
                int jj = e >> 7, rr = e & 127;
                float sv = sm[O_PS + jj * 128 + rr] + sm[O_PS + (6 + jj) * 128 + rr]
                         + sm[O_PS + (12 + jj) * 128 + rr] + sm[O_PS + (18 + jj) * 128 + rr];
                sm[O_T + jj * 128 + rr] = sm[O_SG1 + rr] * sv;
            }
        }
        __syncthreads();
        // ---- S5: psum[c][j][r] = W1[row-pair] . T1_j ----
        {
            float a0[6] = {0,0,0,0,0,0}, a1[6] = {0,0,0,0,0,0};
            const float4* T4 = (const float4*)(sm + O_T);
            #pragma unroll
            for (int q = 0; q < 8; ++q) {
                int qq = c4 * 8 + (q ^ key);
                float4 we = W14[(2 * rp) * 32 + qq];
                float4 wo = W14[(2 * rp + 1) * 32 + qq];
                #pragma unroll
                for (int j = 0; j < 6; ++j) {
                    float4 u = T4[j * 32 + qq];
                    a0[j] = dot4(we, u, a0[j]); a1[j] = dot4(wo, u, a1[j]);
                }
            }
            #pragma unroll
            for (int j = 0; j < 6; ++j)
                *(float2*)&sm[O_PS + (c4 * 6 + j) * 128 + 2 * rp] = make_float2(a0[j], a1[j]);
        }
        __syncthreads();
        // ---- R5: T2[j][r] = sg2[r] * sum_c  (into O_U) ----
        {
            #pragma unroll
            for (int s = 0; s < 3; ++s) {
                int e = tid + s * 256;
                int jj = e >> 7, rr = e & 127;
                float sv = sm[O_PS + jj * 128 + rr] + sm[O_PS + (6 + jj) * 128 + rr]
                         + sm[O_PS + (12 + jj) * 128 + rr] + sm[O_PS + (18 + jj) * 128 + rr];
                sm[O_U + jj * 128 + rr] = sm[O_SG2 + rr] * sv;
            }
        }
        __syncthreads();
        // ---- S6: bterm rows {tid, tid+256, tid+512} = (1-V^2)*(W2row . T2_j) ----
        {
            float acc0 = 0.f, acc1 = 0.f, acc2 = 0.f;
            const float4* T2a = (const float4*)(sm + O_U) + jr0 * 32;
            const float4* T2b = (const float4*)(sm + O_U) + (2 + jr0) * 32;
            const float4* T2c = (const float4*)(sm + O_U) + (4 + jr0) * 32;
            W2_FOREACH(S6_Q)
            sm[O_T + tid]       = (1.f - vl0 * vl0) * acc0;
            sm[O_T + tid + 256] = (1.f - vl1 * vl1) * acc1;
            sm[O_T + tid + 512] = (1.f - vl2 * vl2) * acc2;
        }
        __syncthreads();
        // ---- H: h update + hist; write prefetched sig ----
        if (tid < 128) {
            float xh = sm[O_H + (p ^ 1) * 128 + tid];
            #pragma unroll
            for (int j = 0; j < 6; ++j) xh += sm[O_T + j * 128 + tid];
            sm[O_H + (p ^ 1) * 128 + tid] = xh;
            g_hist[(b * (NW + 1) + t + 1) * 128 + tid] = xh;
        }
        if (tid >= 192) {
            int q = tid - 192;
            if (q < 42 && t + 1 < NW)
                sm[O_SIG + ((t + 1) & 1) * 44 + q] = rsig;
        }
        p ^= 1;
        __syncthreads();
    }
}

// ---- K4: readout ----
__global__ __launch_bounds__(384) void k_read(const float* __restrict__ Wr,
                                              const float* __restrict__ br,
                                              float* __restrict__ out) {
    const int b = blockIdx.x, e = threadIdx.x;
    if (e < (NW + 1) * OUTD) {
        int t = e / OUTD, o = e % OUTD;
        float z = br[o];
        const float4* hrow = (const float4*)&g_hist[(b * (NW + 1) + t) * 128];
        const float4* wrow = (const float4*)&Wr[o * 128];
        float z0 = 0, z1 = 0, z2 = 0, z3 = 0;
        #pragma unroll 8
        for (int s4 = 0; s4 < 32; ++s4) {
            float4 hv = hrow[s4]; float4 wv = wrow[s4];
            z0 = fmaf(hv.x, wv.x, z0); z1 = fmaf(hv.y, wv.y, z1);
            z2 = fmaf(hv.z, wv.z, z2); z3 = fmaf(hv.w, wv.w, z3);
        }
        out[(b * (NW + 1) + t) * OUTD + o] = z + ((z0 + z1) + (z2 + z3));
    }
}

extern "C" void kernel_launch(void* const* d_in, const int* in_sizes, int n_in,
                              void* d_out, int out_size, void* d_ws, size_t ws_size,
                              hipStream_t stream) {
    const float* x   = (const float*)d_in[0];
    const float* Wi0 = (const float*)d_in[1];
    const float* bi0 = (const float*)d_in[2];
    const float* Wi1 = (const float*)d_in[3];
    const float* bi1 = (const float*)d_in[4];
    const float* Wi2 = (const float*)d_in[5];
    const float* bi2 = (const float*)d_in[6];
    const float* Wv0 = (const float*)d_in[7];
    const float* bv0 = (const float*)d_in[8];
    const float* Wv1 = (const float*)d_in[9];
    const float* bv1 = (const float*)d_in[10];
    const float* Wv2 = (const float*)d_in[11];
    const float* bv2 = (const float*)d_in[12];
    const float* Wr  = (const float*)d_in[13];
    const float* br  = (const float*)d_in[14];
    float* out = (float*)d_out;

    hipLaunchKernelGGL(k_sig,  dim3(BB), dim3(256), 0, stream,
                       x, Wi0, bi0, Wi1, bi1, Wi2, bi2);
    hipLaunchKernelGGL(k_scan, dim3(BB), dim3(256), 0, stream,
                       bv0, bv1, bv2, Wv0, Wv1, Wv2);
    hipLaunchKernelGGL(k_read, dim3(BB), dim3(384), 0, stream, Wr, br, out);
}

// Round 8
// 476.504 us; speedup vs baseline: 1.5111x; 1.3044x over previous
//
#include <hip/hip_runtime.h>
#include <math.h>

#define D    6
#define S    128
#define H    128
#define WIN  16
#define BB   8
#define TT   513
#define NW   32
#define OUTD 10

// ---- device-global scratch ----
__device__ float g_lvl1[BB * NW * D];
__device__ float g_area[BB * NW * D * D];
__device__ float g_h0[BB * S];
__device__ float g_hist[BB * (NW + 1) * S];

__device__ __forceinline__ float sp(float x) {
    return (x > 20.f) ? x : log1pf(expf(x));
}
__device__ __forceinline__ float sigm(float x) {
    return 1.f / (1.f + expf(-x));
}
__device__ __forceinline__ float dot4(float4 a, float4 b, float acc) {
    return fmaf(a.x, b.x, fmaf(a.y, b.y, fmaf(a.z, b.z, fmaf(a.w, b.w, acc))));
}

// ---- LDS layout (float offsets) ----
#define O_W0   0        // [128 r][128 k] fp32 row-major
#define O_W1   16384
#define O_PS   32768    // psum [4 c][6 j][128 r] (3072); aliased psumV [2][768]
#define O_U    35840    // [6][128] tangents U ; later T2
#define O_T    36608    // [6][128] T1 ; later bterm [768]
#define O_V    37376    // [768]
#define O_H    38144    // h double buffer [2][128]
#define O_U1   38400
#define O_U2   38528
#define O_SG1  38656
#define O_SG2  38784
#define O_B0   38912
#define O_B1   39040
#define O_SIG  39168    // [2][44]
#define SMTOT  39256    // 157,024 B

// ---- K2: windowed log-signature + init MLP ----
__global__ __launch_bounds__(256) void k_sig(
        const float* __restrict__ x,
        const float* __restrict__ Wi0, const float* __restrict__ bi0,
        const float* __restrict__ Wi1, const float* __restrict__ bi1,
        const float* __restrict__ Wi2, const float* __restrict__ bi2) {
    const int b = blockIdx.x;
    const int tid = threadIdx.x;
    __shared__ float dxs[NW][WIN][D];
    __shared__ float cums[NW][WIN][D];
    __shared__ float ua[H], ub[H];

    const float* xb = x + (size_t)b * TT * D;

    if (tid < NW * D) {
        int w = tid / D, i = tid % D;
        float run = 0.f;
        float prev = xb[(w * WIN) * D + i];
        for (int k = 0; k < WIN; ++k) {
            float cur = xb[(w * WIN + k + 1) * D + i];
            float d = cur - prev; prev = cur;
            dxs[w][k][i] = d;
            cums[w][k][i] = run;
            run += d;
        }
        g_lvl1[(b * NW + w) * D + i] = run;
    }
    __syncthreads();
    for (int e = tid; e < NW * D * D; e += blockDim.x) {
        int w = e / (D * D); int rem = e % (D * D);
        int i = rem / D, j = rem % D;
        float s = 0.f;
        for (int k = 0; k < WIN; ++k)
            s += cums[w][k][i] * dxs[w][k][j] - cums[w][k][j] * dxs[w][k][i];
        g_area[(b * NW + w) * (D * D) + rem] = 0.5f * s;
    }
    if (tid < H) {
        float z = bi0[tid];
        for (int k = 0; k < D; ++k) z += Wi0[tid * D + k] * xb[k];
        ua[tid] = sp(z);
    }
    __syncthreads();
    if (tid < H) {
        float z = bi1[tid];
        for (int k = 0; k < H; ++k) z += Wi1[tid * H + k] * ua[k];
        ub[tid] = sp(z);
    }
    __syncthreads();
    if (tid < H) {
        float z = bi2[tid];
        for (int k = 0; k < H; ++k) z += Wi2[tid * H + k] * ub[k];
        g_h0[b * S + tid] = z;
    }
}

// ---- W2: 48 NAMED float4 per thread = 3 half-rows (kh=tid&1) ----
#define FOR16(X) X(0) X(1) X(2) X(3) X(4) X(5) X(6) X(7) \
                 X(8) X(9) X(10) X(11) X(12) X(13) X(14) X(15)
#define DECL_ABC(q) float4 wA##q, wB##q, wC##q;
#define LOAD_ABC(q) wA##q = W24[baseA + q]; wB##q = W24[baseB + q]; wC##q = W24[baseC + q];
#define S3_Q(q) { float4 u = U24[q]; \
    acc0 = dot4(wA##q, u, acc0); acc1 = dot4(wB##q, u, acc1); acc2 = dot4(wC##q, u, acc2); }
#define S6_Q(q) { \
    acc0 = dot4(wA##q, TA[q], acc0); acc1 = dot4(wB##q, TB[q], acc1); acc2 = dot4(wC##q, TC[q], acc2); }

// ---- K3: the scan: 512 threads (8 waves, 2/SIMD), W2 register-resident ----
__global__ __launch_bounds__(512, 2) void k_scan(
        const float* __restrict__ bv0, const float* __restrict__ bv1,
        const float* __restrict__ bv2,
        const float* __restrict__ Wv0, const float* __restrict__ Wv1,
        const float* __restrict__ Wv2) {
    __shared__ float sm[SMTOT];
    const int b = blockIdx.x, tid = threadIdx.x;
    const int r   = tid & 127;       // row for W0/W1 psum stages
    const int c4  = tid >> 7;        // k-chunk 0..3
    const int key = r & 7;
    // W2 ownership: k-half and 3 rows
    const int kh = tid & 1;
    const int r0 = tid >> 1, r1 = r0 + 256, r2 = r0 + 512;
    const int jA = tid >> 8, jB = 2 + jA, jC = 4 + jA;   // j-blocks of r0,r1,r2

    // stage W0, W1 into LDS (row-major, verbatim)
    {
        float4* d = (float4*)(sm + O_W0);
        const float4* s0 = (const float4*)Wv0;
        const float4* s1 = (const float4*)Wv1;
        for (int i = tid; i < 4096; i += 512) { d[i] = s0[i]; d[4096 + i] = s1[i]; }
    }
    // W2 half-rows in 48 named float4 registers
    FOR16(DECL_ABC)
    const float4* W24 = (const float4*)Wv2;   // [768][32]
    const int baseA = r0 * 32 + kh * 16;
    const int baseB = r1 * 32 + kh * 16;
    const int baseC = r2 * 32 + kh * 16;
    FOR16(LOAD_ABC)
    if (tid < 128) {
        sm[O_B0 + tid] = bv0[tid]; sm[O_B1 + tid] = bv1[tid];
        float h0v = g_h0[b * 128 + tid];
        sm[O_H + tid] = h0v;
        g_hist[(b * (NW + 1)) * 128 + tid] = h0v;
    }
    if (tid >= 448) {               // sig for t=0 into buf 0
        int q = tid - 448;
        if (q < 42)
            sm[O_SIG + q] = (q < 6) ? g_lvl1[(b * NW) * 6 + q]
                                    : g_area[(b * NW) * 36 + q - 6];
    }
    __syncthreads();

    const float4* W04 = (const float4*)(sm + O_W0);
    const float4* W14 = (const float4*)(sm + O_W1);

    int p = 0;
    for (int t = 0; t < NW; ++t) {
        // prefetch sig for step t+1 into registers (written at H phase)
        float rsig = 0.f;
        if (tid >= 448) {
            int q = tid - 448;
            if (q < 42 && t + 1 < NW)
                rsig = (q < 6) ? g_lvl1[(b * NW + t + 1) * 6 + q]
                               : g_area[(b * NW + t + 1) * 36 + q - 6];
        }
        const int sb = O_SIG + (t & 1) * 44;

        // ---- S1: psum[c4][0][r] = W0[r, chunk c4] . h ----
        {
            float a = 0.f;
            const float4* H4 = (const float4*)(sm + O_H + p * 128);
            #pragma unroll
            for (int q = 0; q < 8; ++q) {
                int qq = c4 * 8 + (q ^ key);
                a = dot4(W04[r * 32 + qq], H4[qq], a);
            }
            sm[O_PS + (c4 * 6) * 128 + r] = a;
        }
        __syncthreads();
        // ---- R1 ----
        if (tid < 128) {
            float z = sm[O_B0 + tid];
            #pragma unroll
            for (int c = 0; c < 4; ++c) z += sm[O_PS + (c * 6) * 128 + tid];
            sm[O_U1 + tid] = sp(z); sm[O_SG1 + tid] = sigm(z);
        }
        __syncthreads();
        // ---- S2 ----
        {
            float a = 0.f;
            const float4* U14 = (const float4*)(sm + O_U1);
            #pragma unroll
            for (int q = 0; q < 8; ++q) {
                int qq = c4 * 8 + (q ^ key);
                a = dot4(W14[r * 32 + qq], U14[qq], a);
            }
            sm[O_PS + (c4 * 6) * 128 + r] = a;
        }
        __syncthreads();
        // ---- R2 ----
        if (tid < 128) {
            float z = sm[O_B1 + tid];
            #pragma unroll
            for (int c = 0; c < 4; ++c) z += sm[O_PS + (c * 6) * 128 + tid];
            sm[O_U2 + tid] = sp(z); sm[O_SG2 + tid] = sigm(z);
        }
        __syncthreads();
        // ---- S3: psumV[kh][row] for rows r0,r1,r2 (register W2) ----
        {
            float acc0 = 0.f, acc1 = 0.f, acc2 = 0.f;
            const float4* U24 = (const float4*)(sm + O_U2) + kh * 16;
            FOR16(S3_Q)
            sm[O_PS + kh * 768 + r0] = acc0;
            sm[O_PS + kh * 768 + r1] = acc1;
            sm[O_PS + kh * 768 + r2] = acc2;
        }
        __syncthreads();
        // ---- R3: V[row] = tanh(b2 + half0 + half1), rows tid and tid+512 ----
        {
            sm[O_V + tid] = tanhf(bv2[tid] + sm[O_PS + tid] + sm[O_PS + 768 + tid]);
            if (tid < 256) {
                int e = tid + 512;
                sm[O_V + e] = tanhf(bv2[e] + sm[O_PS + e] + sm[O_PS + 768 + e]);
            }
        }
        __syncthreads();
        // ---- UF: U[j][r] = sum_i area[i][j] V[i*128+r]; h-next init ----
        {
            #pragma unroll
            for (int s = 0; s < 2; ++s) {
                int e = tid + s * 512;
                if (s == 0 || tid < 256) {
                    int jj = e >> 7, rr = e & 127;
                    float u = 0.f;
                    #pragma unroll
                    for (int i = 0; i < 6; ++i)
                        u = fmaf(sm[sb + 6 + i * 6 + jj], sm[O_V + i * 128 + rr], u);
                    sm[O_U + jj * 128 + rr] = u;
                }
            }
            if (tid < 128) {
                float xh = sm[O_H + p * 128 + tid];
                #pragma unroll
                for (int i = 0; i < 6; ++i)
                    xh = fmaf(sm[sb + i], sm[O_V + i * 128 + tid], xh);
                sm[O_H + (p ^ 1) * 128 + tid] = xh;
            }
        }
        __syncthreads();
        // ---- S4: psum[c4][j][r] = W0[r, chunk] . U_j ----
        {
            float a0 = 0.f, a1 = 0.f, a2 = 0.f, a3 = 0.f, a4 = 0.f, a5 = 0.f;
            const float4* U4 = (const float4*)(sm + O_U);
            #pragma unroll
            for (int q = 0; q < 8; ++q) {
                int qq = c4 * 8 + (q ^ key);
                float4 w = W04[r * 32 + qq];
                a0 = dot4(w, U4[qq], a0);
                a1 = dot4(w, U4[32 + qq], a1);
                a2 = dot4(w, U4[64 + qq], a2);
                a3 = dot4(w, U4[96 + qq], a3);
                a4 = dot4(w, U4[128 + qq], a4);
                a5 = dot4(w, U4[160 + qq], a5);
            }
            sm[O_PS + (c4 * 6 + 0) * 128 + r] = a0;
            sm[O_PS + (c4 * 6 + 1) * 128 + r] = a1;
            sm[O_PS + (c4 * 6 + 2) * 128 + r] = a2;
            sm[O_PS + (c4 * 6 + 3) * 128 + r] = a3;
            sm[O_PS + (c4 * 6 + 4) * 128 + r] = a4;
            sm[O_PS + (c4 * 6 + 5) * 128 + r] = a5;
        }
        __syncthreads();
        // ---- R4: T1[j][r] = sg1[r] * sum_c ----
        {
            #pragma unroll
            for (int s = 0; s < 2; ++s) {
                int e = tid + s * 512;
                if (s == 0 || tid < 256) {
                    int jj = e >> 7, rr = e & 127;
                    float sv = sm[O_PS + jj * 128 + rr] + sm[O_PS + (6 + jj) * 128 + rr]
                             + sm[O_PS + (12 + jj) * 128 + rr] + sm[O_PS + (18 + jj) * 128 + rr];
                    sm[O_T + jj * 128 + rr] = sm[O_SG1 + rr] * sv;
                }
            }
        }
        __syncthreads();
        // ---- S5: psum[c4][j][r] = W1[r, chunk] . T1_j ----
        {
            float a0 = 0.f, a1 = 0.f, a2 = 0.f, a3 = 0.f, a4 = 0.f, a5 = 0.f;
            const float4* T4 = (const float4*)(sm + O_T);
            #pragma unroll
            for (int q = 0; q < 8; ++q) {
                int qq = c4 * 8 + (q ^ key);
                float4 w = W14[r * 32 + qq];
                a0 = dot4(w, T4[qq], a0);
                a1 = dot4(w, T4[32 + qq], a1);
                a2 = dot4(w, T4[64 + qq], a2);
                a3 = dot4(w, T4[96 + qq], a3);
                a4 = dot4(w, T4[128 + qq], a4);
                a5 = dot4(w, T4[160 + qq], a5);
            }
            sm[O_PS + (c4 * 6 + 0) * 128 + r] = a0;
            sm[O_PS + (c4 * 6 + 1) * 128 + r] = a1;
            sm[O_PS + (c4 * 6 + 2) * 128 + r] = a2;
            sm[O_PS + (c4 * 6 + 3) * 128 + r] = a3;
            sm[O_PS + (c4 * 6 + 4) * 128 + r] = a4;
            sm[O_PS + (c4 * 6 + 5) * 128 + r] = a5;
        }
        __syncthreads();
        // ---- R5: T2[j][r] = sg2[r] * sum_c  (into O_U) ----
        {
            #pragma unroll
            for (int s = 0; s < 2; ++s) {
                int e = tid + s * 512;
                if (s == 0 || tid < 256) {
                    int jj = e >> 7, rr = e & 127;
                    float sv = sm[O_PS + jj * 128 + rr] + sm[O_PS + (6 + jj) * 128 + rr]
                             + sm[O_PS + (12 + jj) * 128 + rr] + sm[O_PS + (18 + jj) * 128 + rr];
                    sm[O_U + jj * 128 + rr] = sm[O_SG2 + rr] * sv;
                }
            }
        }
        __syncthreads();
        // ---- S6: psumV[kh][row] = W2rows . T2_{j(row)} ----
        {
            float acc0 = 0.f, acc1 = 0.f, acc2 = 0.f;
            const float4* TA = (const float4*)(sm + O_U) + jA * 32 + kh * 16;
            const float4* TB = (const float4*)(sm + O_U) + jB * 32 + kh * 16;
            const float4* TC = (const float4*)(sm + O_U) + jC * 32 + kh * 16;
            FOR16(S6_Q)
            sm[O_PS + kh * 768 + r0] = acc0;
            sm[O_PS + kh * 768 + r1] = acc1;
            sm[O_PS + kh * 768 + r2] = acc2;
        }
        __syncthreads();
        // ---- R6: bterm[row] = (1-V^2)*(half0+half1) (into O_T) ----
        {
            float v = sm[O_V + tid];
            sm[O_T + tid] = (1.f - v * v) * (sm[O_PS + tid] + sm[O_PS + 768 + tid]);
            if (tid < 256) {
                int e = tid + 512;
                float v2 = sm[O_V + e];
                sm[O_T + e] = (1.f - v2 * v2) * (sm[O_PS + e] + sm[O_PS + 768 + e]);
            }
        }
        __syncthreads();
        // ---- H: h update + hist; write prefetched sig ----
        if (tid < 128) {
            float xh = sm[O_H + (p ^ 1) * 128 + tid];
            #pragma unroll
            for (int j = 0; j < 6; ++j) xh += sm[O_T + j * 128 + tid];
            sm[O_H + (p ^ 1) * 128 + tid] = xh;
            g_hist[(b * (NW + 1) + t + 1) * 128 + tid] = xh;
        }
        if (tid >= 448) {
            int q = tid - 448;
            if (q < 42 && t + 1 < NW)
                sm[O_SIG + ((t + 1) & 1) * 44 + q] = rsig;
        }
        p ^= 1;
        __syncthreads();
    }
}

// ---- K4: readout ----
__global__ __launch_bounds__(384) void k_read(const float* __restrict__ Wr,
                                              const float* __restrict__ br,
                                              float* __restrict__ out) {
    const int b = blockIdx.x, e = threadIdx.x;
    if (e < (NW + 1) * OUTD) {
        int t = e / OUTD, o = e % OUTD;
        float z = br[o];
        const float4* hrow = (const float4*)&g_hist[(b * (NW + 1) + t) * 128];
        const float4* wrow = (const float4*)&Wr[o * 128];
        float z0 = 0, z1 = 0, z2 = 0, z3 = 0;
        #pragma unroll 8
        for (int s4 = 0; s4 < 32; ++s4) {
            float4 hv = hrow[s4]; float4 wv = wrow[s4];
            z0 = fmaf(hv.x, wv.x, z0); z1 = fmaf(hv.y, wv.y, z1);
            z2 = fmaf(hv.z, wv.z, z2); z3 = fmaf(hv.w, wv.w, z3);
        }
        out[(b * (NW + 1) + t) * OUTD + o] = z + ((z0 + z1) + (z2 + z3));
    }
}

extern "C" void kernel_launch(void* const* d_in, const int* in_sizes, int n_in,
                              void* d_out, int out_size, void* d_ws, size_t ws_size,
                              hipStream_t stream) {
    const float* x   = (const float*)d_in[0];
    const float* Wi0 = (const float*)d_in[1];
    const float* bi0 = (const float*)d_in[2];
    const float* Wi1 = (const float*)d_in[3];
    const float* bi1 = (const float*)d_in[4];
    const float* Wi2 = (const float*)d_in[5];
    const float* bi2 = (const float*)d_in[6];
    const float* Wv0 = (const float*)d_in[7];
    const float* bv0 = (const float*)d_in[8];
    const float* Wv1 = (const float*)d_in[9];
    const float* bv1 = (const float*)d_in[10];
    const float* Wv2 = (const float*)d_in[11];
    const float* bv2 = (const float*)d_in[12];
    const float* Wr  = (const float*)d_in[13];
    const float* br  = (const float*)d_in[14];
    float* out = (float*)d_out;

    hipLaunchKernelGGL(k_sig,  dim3(BB), dim3(256), 0, stream,
                       x, Wi0, bi0, Wi1, bi1, Wi2, bi2);
    hipLaunchKernelGGL(k_scan, dim3(BB), dim3(512), 0, stream,
                       bv0, bv1, bv2, Wv0, Wv1, Wv2);
    hipLaunchKernelGGL(k_read, dim3(BB), dim3(384), 0, stream, Wr, br, out);
}